// Round 5
// baseline (302.760 us; speedup 1.0000x reference)
//
#include <hip/hip_runtime.h>
#include <cstdint>
#include <cstddef>

// Problem constants
constexpr int B = 32, C = 256, H = 32, W = 32;
constexpr int NPTS = B * H * W;          // 32768 points
constexpr int DIM  = 256;                // embedding dim
constexpr int K    = 1024;               // codebook size
constexpr int QELEMS = B * C * H * W;    // 8388608 quantized elements
constexpr int CHW = C * H * W;           // 262144

typedef __attribute__((ext_vector_type(8))) short s8v;    // 8 bf16 (4 VGPRs)
typedef __attribute__((ext_vector_type(4))) float f32x4;  // MFMA acc / native vec4

// Async global->LDS, 16B per lane. LDS dest is wave-uniform base + lane*16;
// global source address is per-lane.
#define GLD_LDS16(g, l)                                                        \
  __builtin_amdgcn_global_load_lds(                                            \
      (const __attribute__((address_space(1))) unsigned int*)(g),              \
      (__attribute__((address_space(3))) unsigned int*)(l), 16, 0, 0)

__device__ __forceinline__ unsigned short f2bf(float f) {  // RNE fp32->bf16
  unsigned u = __float_as_uint(f);
  return (unsigned short)((u + 0x7FFFu + ((u >> 16) & 1u)) >> 16);
}

// Non-temporal stores: bypass L2 allocation -> no dirty-poison victim
// evictions on the critical path. enc/outq are write-once, never re-read.
// NOTE: __builtin_nontemporal_store requires NATIVE vector types (ext_vector),
// not HIP_vector_type -> use f32x4 here (round-4 compile fix).
__device__ __forceinline__ void nt_store4(float* p, f32x4 v) {
  __builtin_nontemporal_store(v, (f32x4*)p);
}
__device__ __forceinline__ void nt_store1(float* p, float v) {
  __builtin_nontemporal_store(v, p);
}

// ---------------- prep: eprep (16 blocks) + xprep (1024 blocks) -------------
// Unchanged (proven chains; ~13 us).
__global__ __launch_bounds__(256) void prep_kernel(
    const float* __restrict__ x, const float* __restrict__ emb,
    unsigned short* __restrict__ ehi, float* __restrict__ esq,
    unsigned short* __restrict__ xhi, float* __restrict__ xsq) {
  __shared__ float xls[DIM][32];   // 32 KB; eprep uses first 1 KB as sums[4][64]
  const int t = threadIdx.x;
  const int bid = blockIdx.x;

  if (bid < 16) {   // ---- eprep: unchanged chain ----
    float (*sums)[64] = (float (*)[64])xls;
    const int k = bid * 64 + (t & 63);
    const int seg = t >> 6;                     // 4 segs x 64 c
    const float* er = emb + (size_t)k * DIM + seg * 64;
    float v[64];
    float4* v4 = (float4*)v;
#pragma unroll
    for (int i = 0; i < 16; ++i) v4[i] = *(const float4*)(er + i * 4);
    float s = 0.f;
#pragma unroll
    for (int i = 0; i < 64; ++i) s = fmaf(v[i], v[i], s);
    unsigned short* eo = ehi + (size_t)k * DIM + seg * 64;
#pragma unroll
    for (int i = 0; i < 8; ++i) {
      unsigned short h[8];
#pragma unroll
      for (int j = 0; j < 8; ++j) h[j] = f2bf(v[i * 8 + j]);
      *(s8v*)(eo + i * 8) = *(s8v*)h;
    }
    sums[seg][t & 63] = s;
    __syncthreads();
    if (t < 64)
      esq[bid * 64 + t] =
          ((sums[0][t] + sums[1][t]) + sums[2][t]) + sums[3][t];
    return;
  }

  // ---- xprep: 32 points, async staged ----
  const int n0 = (bid - 16) * 32;               // 1024 x-blocks
  const int bb = n0 >> 10, hw0 = n0 & 1023;
  const float* xb = x + (size_t)bb * CHW + hw0;
  const int lane = t & 63, w = t >> 6;
  const int row_off = lane >> 3;                // 8 rows per 1 KB instr
  const int p4 = (lane & 7) * 4;                // float offset within 128B row
#pragma unroll
  for (int i = 0; i < 8; ++i) {
    const int c0 = w * 64 + i * 8;              // wave-uniform
    GLD_LDS16(xb + (size_t)(c0 + row_off) * 1024 + p4, &xls[c0][0]);
  }
  __syncthreads();   // drains vmcnt: tile visible

  if (t < 32) {   // xsq chain: same per-point fp32 fmaf, c ascending
    float s = 0.f;
#pragma unroll 8
    for (int c = 0; c < 256; ++c) {
      const float v = xls[c][t];
      s = fmaf(v, v, s);
    }
    xsq[n0 + t] = s;
  }
  // xhi: p2 = t&31 keeps LDS reads bank-conflict-free (bank = lane&31)
  const int p2 = t & 31, cb = (t >> 5) * 32;
  unsigned short* xo = xhi + (size_t)(n0 + p2) * DIM + cb;
#pragma unroll
  for (int i = 0; i < 4; ++i) {
    unsigned short h[8];
#pragma unroll
    for (int j = 0; j < 8; ++j) h[j] = f2bf(xls[cb + i * 8 + j][p2]);
    *(s8v*)(xo + i * 8) = *(s8v*)h;
  }
}

// ---------------- coarse argmin: bf16 MFMA + candidate emission -------------
// Unchanged round-0 form (~9 us).
constexpr float MARGIN = 1e-3f;
__global__ __launch_bounds__(256) void coarse_kernel(
    const unsigned short* __restrict__ xhi, const unsigned short* __restrict__ ehi,
    const float* __restrict__ esq, const float* __restrict__ xsq,
    float* __restrict__ part, unsigned int* __restrict__ cand) {
  __shared__ __align__(16) unsigned short xs[128][32];   // 8 KB
  __shared__ __align__(16) unsigned short es[128][32];   // 8 KB
  __shared__ float xsq_s[128], esq_s[128], thr_s[128];
  __shared__ unsigned long long red2[2][128];
  __shared__ unsigned int cntL[128];

  const int t = threadIdx.x;
  const int lane = t & 63, w = t >> 6;
  const int wn = (w & 1) * 64, wk = (w >> 1) * 64;
  const int col = lane & 15, quad = lane >> 4;
  const int nblk = blockIdx.x * 128;
  const int kblk = blockIdx.y * 128;

  if (t < 128) {
    xsq_s[t] = xsq[nblk + t];
    esq_s[t] = esq[kblk + t];
    cntL[t] = 0u;
  }

  f32x4 acc[4][4];
#pragma unroll
  for (int i = 0; i < 4; ++i)
#pragma unroll
    for (int j = 0; j < 4; ++j) acc[i][j] = (f32x4){0.f, 0.f, 0.f, 0.f};

  const int gl_row = lane >> 2;        // row within 16-row staging inst
  const int gl_c   = (lane & 3) * 8;   // bf16 col offset

  for (int c0 = 0; c0 < DIM; c0 += 32) {
    __syncthreads();   // previous tile fully consumed (drains lgkm+vm)
#pragma unroll
    for (int i = 0; i < 2; ++i) {
      const int inst = w + 4 * i;                 // wave-uniform
      const int row = inst * 16 + gl_row;
      GLD_LDS16(xhi + (size_t)(nblk + row) * DIM + c0 + gl_c, &xs[inst * 16][0]);
      GLD_LDS16(ehi + (size_t)(kblk + row) * DIM + c0 + gl_c, &es[inst * 16][0]);
    }
    __syncthreads();   // vmcnt(0): tiles visible
    s8v a[4], b[4];
#pragma unroll
    for (int ti = 0; ti < 4; ++ti)
      a[ti] = *(const s8v*)&xs[wn + ti * 16 + col][quad * 8];
#pragma unroll
    for (int tj = 0; tj < 4; ++tj)
      b[tj] = *(const s8v*)&es[wk + tj * 16 + col][quad * 8];
#pragma unroll
    for (int ti = 0; ti < 4; ++ti)
#pragma unroll
      for (int tj = 0; tj < 4; ++tj)
        acc[ti][tj] = __builtin_amdgcn_mfma_f32_16x16x32_bf16(
            a[ti], b[tj], acc[ti][tj], 0, 0, 0);
  }

  // fold: per-thread per-n packed (d,k) min over its 4 k-tiles
  unsigned long long nmin[4][4];
#pragma unroll
  for (int ti = 0; ti < 4; ++ti)
#pragma unroll
    for (int r = 0; r < 4; ++r) nmin[ti][r] = ~0ULL;
#pragma unroll
  for (int ti = 0; ti < 4; ++ti)
#pragma unroll
    for (int tj = 0; tj < 4; ++tj) {
      const int krel = wk + tj * 16 + col;
      const float eq = esq_s[krel];
#pragma unroll
      for (int r = 0; r < 4; ++r) {
        const int nl = wn + ti * 16 + quad * 4 + r;
        const float d = (xsq_s[nl] + eq) - 2.f * acc[ti][tj][r];
        const unsigned long long key =
            ((unsigned long long)__float_as_uint(d) << 32) |
            (unsigned)(kblk + krel);
        if (key < nmin[ti][r]) nmin[ti][r] = key;   // d>0 -> uint-monotone
      }
    }
  // butterfly over the 16 cols (stays within quad)
#pragma unroll
  for (int o = 1; o < 16; o <<= 1)
#pragma unroll
    for (int ti = 0; ti < 4; ++ti)
#pragma unroll
      for (int r = 0; r < 4; ++r) {
        const unsigned long long v = __shfl_xor(nmin[ti][r], o, 64);
        if (v < nmin[ti][r]) nmin[ti][r] = v;
      }
  if (col == 0) {
#pragma unroll
    for (int ti = 0; ti < 4; ++ti)
#pragma unroll
      for (int r = 0; r < 4; ++r)
        red2[w >> 1][wn + ti * 16 + quad * 4 + r] = nmin[ti][r];
  }
  __syncthreads();
  if (t < 128) {
    const unsigned long long m0 = red2[0][t], m1 = red2[1][t];
    const unsigned long long m = (m1 < m0) ? m1 : m0;
    const float dmin = __uint_as_float((unsigned)(m >> 32));
    part[(size_t)(nblk + t) * 8 + blockIdx.y] = dmin;   // split-min
    thr_s[t] = dmin + MARGIN;
  }
  __syncthreads();
  // emission: all k with coarse d <= split_min + M
#pragma unroll
  for (int ti = 0; ti < 4; ++ti)
#pragma unroll
    for (int tj = 0; tj < 4; ++tj) {
      const int krel = wk + tj * 16 + col;
      const float eq = esq_s[krel];
#pragma unroll
      for (int r = 0; r < 4; ++r) {
        const int nl = wn + ti * 16 + quad * 4 + r;
        const float d = (xsq_s[nl] + eq) - 2.f * acc[ti][tj][r];
        if (d <= thr_s[nl]) {
          const unsigned slot = atomicAdd(&cntL[nl], 1u);
          if (slot < 4u)
            cand[((size_t)(nblk + nl) * 8 + blockIdx.y) * 4 + slot] =
                (unsigned)(kblk + krel);
        }
      }
    }
  __syncthreads();
  if (t < 128) {
    unsigned c = cntL[t];
    const size_t base = ((size_t)(nblk + t) * 8 + blockIdx.y) * 4;
    if (c > 4u) { cand[base + 3] = 0xFFFFFFFEu; c = 3u; }  // overflow -> rescan
    for (unsigned s = c; s < 4u; ++s) cand[base + s] = 0xFFFFFFFFu;
  }
}

// ------- resolve: exact argmin -> ids + per-block SUM(dmin) loss partial ----
// 32 points/block (1024 blocks): x-stage reads full 128B lines (lanes 0..31
// contiguous). Score chain verbatim -> identical argmin. dmin IS
// ||x - q||^2 exactly, so loss = 1.25 * SUM(dmin)/QELEMS comes free and the
// downstream kernel never touches x.
__global__ __launch_bounds__(256) void resolve_kernel(
    const float* __restrict__ x, const float* __restrict__ emb,
    const float* __restrict__ esq, const float* __restrict__ xsq,
    const float* __restrict__ part, const unsigned int* __restrict__ cand,
    int* __restrict__ ids_g, float* __restrict__ lws) {
  __shared__ __align__(16) float xls[DIM][33];   // 33.8 KB; pad keeps banks spread
  __shared__ unsigned list[1024];                // bound: 32*8*4 = 1024
  __shared__ unsigned long long best[32];
  __shared__ float thr_s[32];
  __shared__ float xsq_s[32];
  __shared__ int lcnt;

  const int t = threadIdx.x;
  const int n0 = blockIdx.x * 32;
  const int bb = n0 >> 10, hw0 = n0 & 1023;

  // ---- stage x tile: 8 segs x 32 c, lanes 0..31 contiguous = full lines ----
  const float* xb = x + (size_t)bb * CHW + hw0;
  {
    const int p = t & 31, cs = t >> 5;
#pragma unroll 8
    for (int r = 0; r < 32; ++r) {
      const int c = r * 8 + cs;
      xls[c][p] = xb[(size_t)c * 1024 + p];
    }
  }
  if (t == 0) lcnt = 0;
  if (t < 32) {
    best[t] = ~0ULL;
    xsq_s[t] = xsq[n0 + t];
    const float4 p0 = *(const float4*)&part[(size_t)(n0 + t) * 8];
    const float4 p1 = *(const float4*)&part[(size_t)(n0 + t) * 8 + 4];
    float g = fminf(fminf(fminf(p0.x, p0.y), fminf(p0.z, p0.w)),
                    fminf(fminf(p1.x, p1.y), fminf(p1.z, p1.w)));
    thr_s[t] = g + MARGIN;
  }
  __syncthreads();

  // ---- build worklist: thread t -> (point nn = t>>3, split s = t&7) ----
  {
    const int nn = t >> 3, s = t & 7;
    const float pv = part[(size_t)(n0 + nn) * 8 + s];
    if (pv <= thr_s[nn]) {
      const uint4 c4 = *(const uint4*)&cand[((size_t)(n0 + nn) * 8 + s) * 4];
      const unsigned vs[4] = {c4.x, c4.y, c4.z, c4.w};
#pragma unroll
      for (int i = 0; i < 4; ++i) {
        const unsigned v = vs[i];
        if (v == 0xFFFFFFFFu) continue;
        const unsigned entry = (v == 0xFFFFFFFEu)
                                   ? ((unsigned)nn << 11) | 1024u | (unsigned)s
                                   : ((unsigned)nn << 11) | (v & 1023u);
        const int pos = atomicAdd(&lcnt, 1);
        if (pos < 1024) list[pos] = entry;
      }
    }
  }
  __syncthreads();

  // ---- consume worklist; score chain verbatim (bit-identical argmin) ----
  const int L = lcnt < 1024 ? lcnt : 1024;
  for (int e = t; e < L; e += 256) {
    const unsigned entry = list[e];
    const int p = entry >> 11;
    const float xq = xsq_s[p];
    int klo, khi;
    if (entry & 1024u) { const int s = entry & 7; klo = s * 128; khi = klo + 128; }
    else               { klo = entry & 1023u; khi = klo + 1; }
    for (int k = klo; k < khi; ++k) {
      const float* er = emb + (size_t)k * DIM;
      float dot = 0.f;
#pragma unroll 4
      for (int c4 = 0; c4 < DIM; c4 += 4) {
        const float4 e4 = *(const float4*)(er + c4);
        dot = fmaf(xls[c4 + 0][p], e4.x, dot);
        dot = fmaf(xls[c4 + 1][p], e4.y, dot);
        dot = fmaf(xls[c4 + 2][p], e4.z, dot);
        dot = fmaf(xls[c4 + 3][p], e4.w, dot);
      }
      const float t1 = xq + esq[k];
      const float d = t1 - 2.f * dot;
      const unsigned long long key =
          ((unsigned long long)__float_as_uint(d) << 32) | (unsigned)k;
      atomicMin(&best[p], key);   // d>0 -> uint-monotone; low k wins ties
    }
  }
  __syncthreads();
  if (t < 32) {
    ids_g[n0 + t] = (int)(best[t] & 0xFFFFFFFFu);
    // loss partial: dmin = exact ||x_p - e_win||^2
    float s = __uint_as_float((unsigned)(best[t] >> 32));
#pragma unroll
    for (int o = 16; o > 0; o >>= 1) s += __shfl_down(s, o, 64);
    if (t == 0) lws[blockIdx.x] = s;
  }
}

// ------- encq: enc one-hot + outq gather, ALL non-temporal stores -----------
// 1024 blocks x 32 points. Depends only on ids (no x read). nt stores bypass
// L2 allocation -> no dirty-poison victim writebacks on the critical path
// (theory for the ~2 TB/s write wall of rounds 0-3).
__global__ __launch_bounds__(256) void encq_kernel(
    const float* __restrict__ emb, const int* __restrict__ ids_g,
    float* __restrict__ enc, float* __restrict__ outq) {
  __shared__ int ids_s[32];
  const int t = threadIdx.x;
  const int n0 = blockIdx.x * 32;
  const int bb = n0 >> 10, hw0 = n0 & 1023;
  if (t < 32) ids_s[t] = ids_g[n0 + t];
  __syncthreads();

  // ---- enc slice: 32 rows x 1024 = 32768 floats, base === 1 mod 4 ----
  // 16B-aligned float4 region: local floats 3..32766 (8191 groups); edges
  // 0,1,2 (point n0, k=0..2) and 32767 (point n0+31, k=1023) scalar.
  float* sl = enc + (size_t)n0 * K;
  {
    float* b4 = sl + 3;
#pragma unroll
    for (int j = 0; j < 32; ++j) {
      const int idx = t + j * 256;
      if (idx < 8191) {
        const int lf = 3 + 4 * idx;           // local float index of comp 0
        f32x4 v;
        v.x = (((lf + 0) & 1023) == ids_s[(lf + 0) >> 10]) ? 1.f : 0.f;
        v.y = (((lf + 1) & 1023) == ids_s[(lf + 1) >> 10]) ? 1.f : 0.f;
        v.z = (((lf + 2) & 1023) == ids_s[(lf + 2) >> 10]) ? 1.f : 0.f;
        v.w = (((lf + 3) & 1023) == ids_s[(lf + 3) >> 10]) ? 1.f : 0.f;
        nt_store4(b4 + 4 * idx, v);
      }
    }
    if (t == 0) {
      nt_store1(sl + 0, (ids_s[0] == 0) ? 1.f : 0.f);
      nt_store1(sl + 1, (ids_s[0] == 1) ? 1.f : 0.f);
      nt_store1(sl + 2, (ids_s[0] == 2) ? 1.f : 0.f);
      nt_store1(sl + 32767, (ids_s[31] == 1023) ? 1.f : 0.f);
    }
  }

  // ---- outq: thread (p = t&31, g = t>>5) -> emb[id_p][g*32..+31] ----
  // Stores: per instr lanes 0..31 share c -> 128B full line; x2 per wave.
  {
    const int p = t & 31, g = t >> 5;
    const int row = ids_s[p];
    const float* er = emb + (size_t)row * DIM + g * 32;
    float* ob = outq + (size_t)bb * CHW + hw0 + p;
#pragma unroll
    for (int i = 0; i < 8; ++i) {
      const float4 v = *(const float4*)(er + i * 4);
      const int c = g * 32 + i * 4;
      nt_store1(ob + (size_t)(c + 0) * 1024, v.x);
      nt_store1(ob + (size_t)(c + 1) * 1024, v.y);
      nt_store1(ob + (size_t)(c + 2) * 1024, v.z);
      nt_store1(ob + (size_t)(c + 3) * 1024, v.w);
    }
  }
}

// ---- loss_reduce: one block sums the 1024 per-block dmin partials ----
__global__ __launch_bounds__(256) void loss_reduce(
    const float* __restrict__ lws, float* __restrict__ loss) {
  __shared__ float red[4];
  const int t = threadIdx.x;
  float s = 0.f;
#pragma unroll
  for (int i = 0; i < 4; ++i) s += lws[t + i * 256];
#pragma unroll
  for (int o = 32; o > 0; o >>= 1) s += __shfl_down(s, o, 64);
  if ((t & 63) == 0) red[t >> 6] = s;
  __syncthreads();
  if (t == 0)
    *loss = (((red[0] + red[1]) + red[2]) + red[3]) * (1.25f / (float)QELEMS);
}

extern "C" void kernel_launch(void* const* d_in, const int* in_sizes, int n_in,
                              void* d_out, int out_size, void* d_ws, size_t ws_size,
                              hipStream_t stream) {
  const float* x   = (const float*)d_in[0];
  const float* emb = (const float*)d_in[1];
  float* out  = (float*)d_out;
  float* loss = out;                       // [1]
  float* outq = out + 1;                   // [8388608], 4B-aligned only
  float* enc  = out + 1 + QELEMS;          // [33554432], 4B-aligned only

  char* ws = (char*)d_ws;
  unsigned short* ehi  = (unsigned short*)ws;                  // 512 KB
  float*          esq  = (float*)(ws + 524288);                // 4 KB
  float*          xsq  = (float*)(ws + 528384);                // 128 KB
  float*          part = (float*)(ws + 659456);                // 1 MB
  unsigned int*   cand = (unsigned int*)(ws + 1708032);        // 4 MB
  unsigned short* xhi  = (unsigned short*)(ws + 5902336);      // 16 MB
  float*          lws  = (float*)(ws + 22679552);              // 4 KB
  int*            ids  = (int*)(ws + 22683648);                // 128 KB
  // total ws use: ~22.8 MB

  prep_kernel<<<16 + 1024, 256, 0, stream>>>(x, emb, ehi, esq, xhi, xsq);
  dim3 cg(NPTS / 128, 8);
  coarse_kernel<<<cg, 256, 0, stream>>>(xhi, ehi, esq, xsq, part, cand);
  resolve_kernel<<<NPTS / 32, 256, 0, stream>>>(x, emb, esq, xsq, part, cand,
                                                ids, lws);
  encq_kernel<<<NPTS / 32, 256, 0, stream>>>(emb, ids, enc, outq);
  loss_reduce<<<1, 256, 0, stream>>>(lws, loss);
}

// Round 6
// 282.714 us; speedup vs baseline: 1.0709x; 1.0709x over previous
//
#include <hip/hip_runtime.h>
#include <cstdint>
#include <cstddef>

// Problem constants
constexpr int B = 32, C = 256, H = 32, W = 32;
constexpr int NPTS = B * H * W;          // 32768 points
constexpr int DIM  = 256;                // embedding dim
constexpr int K    = 1024;               // codebook size
constexpr int QELEMS = B * C * H * W;    // 8388608 quantized elements
constexpr int CHW = C * H * W;           // 262144

typedef __attribute__((ext_vector_type(8))) short s8v;    // 8 bf16 (4 VGPRs)
typedef __attribute__((ext_vector_type(4))) float f32x4;  // MFMA acc / native vec4

// Async global->LDS, 16B per lane. LDS dest is wave-uniform base + lane*16;
// global source address is per-lane.
#define GLD_LDS16(g, l)                                                        \
  __builtin_amdgcn_global_load_lds(                                            \
      (const __attribute__((address_space(1))) unsigned int*)(g),              \
      (__attribute__((address_space(3))) unsigned int*)(l), 16, 0, 0)

__device__ __forceinline__ unsigned short f2bf(float f) {  // RNE fp32->bf16
  unsigned u = __float_as_uint(f);
  return (unsigned short)((u + 0x7FFFu + ((u >> 16) & 1u)) >> 16);
}

// ---------------- prep: eprep (16 blocks) + xprep (1024 blocks) -------------
// Unchanged (proven chains; ~12 us).
__global__ __launch_bounds__(256) void prep_kernel(
    const float* __restrict__ x, const float* __restrict__ emb,
    unsigned short* __restrict__ ehi, float* __restrict__ esq,
    unsigned short* __restrict__ xhi, float* __restrict__ xsq) {
  __shared__ float xls[DIM][32];   // 32 KB; eprep uses first 1 KB as sums[4][64]
  const int t = threadIdx.x;
  const int bid = blockIdx.x;

  if (bid < 16) {   // ---- eprep: unchanged chain ----
    float (*sums)[64] = (float (*)[64])xls;
    const int k = bid * 64 + (t & 63);
    const int seg = t >> 6;                     // 4 segs x 64 c
    const float* er = emb + (size_t)k * DIM + seg * 64;
    float v[64];
    float4* v4 = (float4*)v;
#pragma unroll
    for (int i = 0; i < 16; ++i) v4[i] = *(const float4*)(er + i * 4);
    float s = 0.f;
#pragma unroll
    for (int i = 0; i < 64; ++i) s = fmaf(v[i], v[i], s);
    unsigned short* eo = ehi + (size_t)k * DIM + seg * 64;
#pragma unroll
    for (int i = 0; i < 8; ++i) {
      unsigned short h[8];
#pragma unroll
      for (int j = 0; j < 8; ++j) h[j] = f2bf(v[i * 8 + j]);
      *(s8v*)(eo + i * 8) = *(s8v*)h;
    }
    sums[seg][t & 63] = s;
    __syncthreads();
    if (t < 64)
      esq[bid * 64 + t] =
          ((sums[0][t] + sums[1][t]) + sums[2][t]) + sums[3][t];
    return;
  }

  // ---- xprep: 32 points, async staged ----
  const int n0 = (bid - 16) * 32;               // 1024 x-blocks
  const int bb = n0 >> 10, hw0 = n0 & 1023;
  const float* xb = x + (size_t)bb * CHW + hw0;
  const int lane = t & 63, w = t >> 6;
  const int row_off = lane >> 3;                // 8 rows per 1 KB instr
  const int p4 = (lane & 7) * 4;                // float offset within 128B row
#pragma unroll
  for (int i = 0; i < 8; ++i) {
    const int c0 = w * 64 + i * 8;              // wave-uniform
    GLD_LDS16(xb + (size_t)(c0 + row_off) * 1024 + p4, &xls[c0][0]);
  }
  __syncthreads();   // drains vmcnt: tile visible

  if (t < 32) {   // xsq chain: same per-point fp32 fmaf, c ascending
    float s = 0.f;
#pragma unroll 8
    for (int c = 0; c < 256; ++c) {
      const float v = xls[c][t];
      s = fmaf(v, v, s);
    }
    xsq[n0 + t] = s;
  }
  // xhi: p2 = t&31 keeps LDS reads bank-conflict-free (bank = lane&31)
  const int p2 = t & 31, cb = (t >> 5) * 32;
  unsigned short* xo = xhi + (size_t)(n0 + p2) * DIM + cb;
#pragma unroll
  for (int i = 0; i < 4; ++i) {
    unsigned short h[8];
#pragma unroll
    for (int j = 0; j < 8; ++j) h[j] = f2bf(xls[cb + i * 8 + j][p2]);
    *(s8v*)(xo + i * 8) = *(s8v*)h;
  }
}

// ---------------- coarse argmin: bf16 MFMA + candidate emission -------------
// Unchanged round-0 form (~9 us).
constexpr float MARGIN = 1e-3f;
__global__ __launch_bounds__(256) void coarse_kernel(
    const unsigned short* __restrict__ xhi, const unsigned short* __restrict__ ehi,
    const float* __restrict__ esq, const float* __restrict__ xsq,
    float* __restrict__ part, unsigned int* __restrict__ cand) {
  __shared__ __align__(16) unsigned short xs[128][32];   // 8 KB
  __shared__ __align__(16) unsigned short es[128][32];   // 8 KB
  __shared__ float xsq_s[128], esq_s[128], thr_s[128];
  __shared__ unsigned long long red2[2][128];
  __shared__ unsigned int cntL[128];

  const int t = threadIdx.x;
  const int lane = t & 63, w = t >> 6;
  const int wn = (w & 1) * 64, wk = (w >> 1) * 64;
  const int col = lane & 15, quad = lane >> 4;
  const int nblk = blockIdx.x * 128;
  const int kblk = blockIdx.y * 128;

  if (t < 128) {
    xsq_s[t] = xsq[nblk + t];
    esq_s[t] = esq[kblk + t];
    cntL[t] = 0u;
  }

  f32x4 acc[4][4];
#pragma unroll
  for (int i = 0; i < 4; ++i)
#pragma unroll
    for (int j = 0; j < 4; ++j) acc[i][j] = (f32x4){0.f, 0.f, 0.f, 0.f};

  const int gl_row = lane >> 2;        // row within 16-row staging inst
  const int gl_c   = (lane & 3) * 8;   // bf16 col offset

  for (int c0 = 0; c0 < DIM; c0 += 32) {
    __syncthreads();   // previous tile fully consumed (drains lgkm+vm)
#pragma unroll
    for (int i = 0; i < 2; ++i) {
      const int inst = w + 4 * i;                 // wave-uniform
      const int row = inst * 16 + gl_row;
      GLD_LDS16(xhi + (size_t)(nblk + row) * DIM + c0 + gl_c, &xs[inst * 16][0]);
      GLD_LDS16(ehi + (size_t)(kblk + row) * DIM + c0 + gl_c, &es[inst * 16][0]);
    }
    __syncthreads();   // vmcnt(0): tiles visible
    s8v a[4], b[4];
#pragma unroll
    for (int ti = 0; ti < 4; ++ti)
      a[ti] = *(const s8v*)&xs[wn + ti * 16 + col][quad * 8];
#pragma unroll
    for (int tj = 0; tj < 4; ++tj)
      b[tj] = *(const s8v*)&es[wk + tj * 16 + col][quad * 8];
#pragma unroll
    for (int ti = 0; ti < 4; ++ti)
#pragma unroll
      for (int tj = 0; tj < 4; ++tj)
        acc[ti][tj] = __builtin_amdgcn_mfma_f32_16x16x32_bf16(
            a[ti], b[tj], acc[ti][tj], 0, 0, 0);
  }

  // fold: per-thread per-n packed (d,k) min over its 4 k-tiles
  unsigned long long nmin[4][4];
#pragma unroll
  for (int ti = 0; ti < 4; ++ti)
#pragma unroll
    for (int r = 0; r < 4; ++r) nmin[ti][r] = ~0ULL;
#pragma unroll
  for (int ti = 0; ti < 4; ++ti)
#pragma unroll
    for (int tj = 0; tj < 4; ++tj) {
      const int krel = wk + tj * 16 + col;
      const float eq = esq_s[krel];
#pragma unroll
      for (int r = 0; r < 4; ++r) {
        const int nl = wn + ti * 16 + quad * 4 + r;
        const float d = (xsq_s[nl] + eq) - 2.f * acc[ti][tj][r];
        const unsigned long long key =
            ((unsigned long long)__float_as_uint(d) << 32) |
            (unsigned)(kblk + krel);
        if (key < nmin[ti][r]) nmin[ti][r] = key;   // d>0 -> uint-monotone
      }
    }
  // butterfly over the 16 cols (stays within quad)
#pragma unroll
  for (int o = 1; o < 16; o <<= 1)
#pragma unroll
    for (int ti = 0; ti < 4; ++ti)
#pragma unroll
      for (int r = 0; r < 4; ++r) {
        const unsigned long long v = __shfl_xor(nmin[ti][r], o, 64);
        if (v < nmin[ti][r]) nmin[ti][r] = v;
      }
  if (col == 0) {
#pragma unroll
    for (int ti = 0; ti < 4; ++ti)
#pragma unroll
      for (int r = 0; r < 4; ++r)
        red2[w >> 1][wn + ti * 16 + quad * 4 + r] = nmin[ti][r];
  }
  __syncthreads();
  if (t < 128) {
    const unsigned long long m0 = red2[0][t], m1 = red2[1][t];
    const unsigned long long m = (m1 < m0) ? m1 : m0;
    const float dmin = __uint_as_float((unsigned)(m >> 32));
    part[(size_t)(nblk + t) * 8 + blockIdx.y] = dmin;   // split-min
    thr_s[t] = dmin + MARGIN;
  }
  __syncthreads();
  // emission: all k with coarse d <= split_min + M
#pragma unroll
  for (int ti = 0; ti < 4; ++ti)
#pragma unroll
    for (int tj = 0; tj < 4; ++tj) {
      const int krel = wk + tj * 16 + col;
      const float eq = esq_s[krel];
#pragma unroll
      for (int r = 0; r < 4; ++r) {
        const int nl = wn + ti * 16 + quad * 4 + r;
        const float d = (xsq_s[nl] + eq) - 2.f * acc[ti][tj][r];
        if (d <= thr_s[nl]) {
          const unsigned slot = atomicAdd(&cntL[nl], 1u);
          if (slot < 4u)
            cand[((size_t)(nblk + nl) * 8 + blockIdx.y) * 4 + slot] =
                (unsigned)(kblk + krel);
        }
      }
    }
  __syncthreads();
  if (t < 128) {
    unsigned c = cntL[t];
    const size_t base = ((size_t)(nblk + t) * 8 + blockIdx.y) * 4;
    if (c > 4u) { cand[base + 3] = 0xFFFFFFFEu; c = 3u; }  // overflow -> rescan
    for (unsigned s = c; s < 4u; ++s) cand[base + s] = 0xFFFFFFFFu;
  }
}

// ------- finish2: exact resolve (parallel rescans) + enc + outq + loss ------
// 32 points/block, 1024 blocks. KEY FIX vs all prior rounds: overflow rescans
// were ONE thread serially scanning 128 k x 256-deep fmaf chain (~131K cyc =
// ~55 us makespan per block; ~4 rescans/block expected -> this was resolve's
// entire ~70 us). Now rescans go to a separate list and are scored ONE K PER
// THREAD (128 threads/rescan, 2 rescans/pass). Per-k score chain is verbatim
// -> bit-identical best[] -> identical ids and loss.
__global__ __launch_bounds__(256) void finish2_kernel(
    const float* __restrict__ x, const float* __restrict__ emb,
    const float* __restrict__ esq, const float* __restrict__ xsq,
    const float* __restrict__ part, const unsigned int* __restrict__ cand,
    float* __restrict__ outq, float* __restrict__ enc,
    float* __restrict__ lws) {
  __shared__ __align__(16) float xls[DIM][33];   // 33.8 KB
  __shared__ unsigned list[1024];                // single-k entries
  __shared__ unsigned rlist[256];                // rescan (nn,s) pairs
  __shared__ unsigned long long best[32];
  __shared__ float thr_s[32];
  __shared__ float xsq_s[32];
  __shared__ int ids_s[32];
  __shared__ int lcnt, rcnt;

  const int t = threadIdx.x;
  const int n0 = blockIdx.x * 32;
  const int bb = n0 >> 10, hw0 = n0 & 1023;

  // ---- stage x tile: lanes 0..31 contiguous = full 128B lines ----
  const float* xb = x + (size_t)bb * CHW + hw0;
  {
    const int p = t & 31, cs = t >> 5;
#pragma unroll 8
    for (int r = 0; r < 32; ++r) {
      const int c = r * 8 + cs;
      xls[c][p] = xb[(size_t)c * 1024 + p];
    }
  }
  if (t == 0) { lcnt = 0; rcnt = 0; }
  if (t < 32) {
    best[t] = ~0ULL;
    xsq_s[t] = xsq[n0 + t];
    const float4 p0 = *(const float4*)&part[(size_t)(n0 + t) * 8];
    const float4 p1 = *(const float4*)&part[(size_t)(n0 + t) * 8 + 4];
    float g = fminf(fminf(fminf(p0.x, p0.y), fminf(p0.z, p0.w)),
                    fminf(fminf(p1.x, p1.y), fminf(p1.z, p1.w)));
    thr_s[t] = g + MARGIN;
  }
  __syncthreads();

  // ---- build worklists: thread t -> (point nn = t>>3, split s = t&7) ----
  {
    const int nn = t >> 3, s = t & 7;
    const float pv = part[(size_t)(n0 + nn) * 8 + s];
    if (pv <= thr_s[nn]) {
      const uint4 c4 = *(const uint4*)&cand[((size_t)(n0 + nn) * 8 + s) * 4];
      if (c4.w == 0xFFFFFFFEu) {
        // overflow: full-split rescan covers all its candidates
        const int rp = atomicAdd(&rcnt, 1);
        if (rp < 256) rlist[rp] = ((unsigned)nn << 3) | (unsigned)s;
      } else {
        const unsigned vs[4] = {c4.x, c4.y, c4.z, c4.w};
#pragma unroll
        for (int i = 0; i < 4; ++i) {
          const unsigned v = vs[i];
          if (v <= 1023u) {
            const int pos = atomicAdd(&lcnt, 1);
            if (pos < 1024) list[pos] = ((unsigned)nn << 11) | v;
          }
        }
      }
    }
  }
  __syncthreads();

  // ---- phase A: single-k entries (score chain verbatim) ----
  const int L = lcnt < 1024 ? lcnt : 1024;
  for (int e = t; e < L; e += 256) {
    const unsigned entry = list[e];
    const int p = entry >> 11;
    const int k = entry & 2047;
    const float xq = xsq_s[p];
    const float* er = emb + (size_t)k * DIM;
    float dot = 0.f;
#pragma unroll 4
    for (int c4 = 0; c4 < DIM; c4 += 4) {
      const float4 e4 = *(const float4*)(er + c4);
      dot = fmaf(xls[c4 + 0][p], e4.x, dot);
      dot = fmaf(xls[c4 + 1][p], e4.y, dot);
      dot = fmaf(xls[c4 + 2][p], e4.z, dot);
      dot = fmaf(xls[c4 + 3][p], e4.w, dot);
    }
    const float t1 = xq + esq[k];
    const float d = t1 - 2.f * dot;
    const unsigned long long key =
        ((unsigned long long)__float_as_uint(d) << 32) | (unsigned)k;
    atomicMin(&best[p], key);   // d>0 -> uint-monotone; low k wins ties
  }

  // ---- phase B: rescans, ONE k PER THREAD (2 rescans per pass) ----
  const int R = rcnt < 256 ? rcnt : 256;
  for (int rb = 0; rb < R; rb += 2) {
    const int ri = rb + (t >> 7);
    if (ri < R) {
      const unsigned rs = rlist[ri];
      const int p = rs >> 3;
      const int k = (int)(rs & 7u) * 128 + (t & 127);
      const float xq = xsq_s[p];
      const float* er = emb + (size_t)k * DIM;
      float dot = 0.f;
#pragma unroll 4
      for (int c4 = 0; c4 < DIM; c4 += 4) {
        const float4 e4 = *(const float4*)(er + c4);
        dot = fmaf(xls[c4 + 0][p], e4.x, dot);
        dot = fmaf(xls[c4 + 1][p], e4.y, dot);
        dot = fmaf(xls[c4 + 2][p], e4.z, dot);
        dot = fmaf(xls[c4 + 3][p], e4.w, dot);
      }
      const float t1 = xq + esq[k];
      const float d = t1 - 2.f * dot;
      const unsigned long long key =
          ((unsigned long long)__float_as_uint(d) << 32) | (unsigned)k;
      atomicMin(&best[p], key);
    }
  }
  __syncthreads();

  if (t < 32) {
    ids_s[t] = (int)(best[t] & 0xFFFFFFFFu);
    // loss partial: dmin = exact ||x_p - e_win||^2 (same value as R5, passed)
    float s = __uint_as_float((unsigned)(best[t] >> 32));
#pragma unroll
    for (int o = 16; o > 0; o >>= 1) s += __shfl_down(s, o, 64);
    if (t == 0) lws[blockIdx.x] = s;
  }
  __syncthreads();

  // ---- enc slice: 32 rows x 1024 floats, base === 1 mod 4 ----
  {
    float* sl = enc + (size_t)n0 * K;
    float* b4 = sl + 3;
#pragma unroll
    for (int j = 0; j < 32; ++j) {
      const int idx = t + j * 256;
      if (idx < 8191) {
        const int lf = 3 + 4 * idx;           // local float index of comp 0
        float4 v;
        v.x = (((lf + 0) & 1023) == ids_s[(lf + 0) >> 10]) ? 1.f : 0.f;
        v.y = (((lf + 1) & 1023) == ids_s[(lf + 1) >> 10]) ? 1.f : 0.f;
        v.z = (((lf + 2) & 1023) == ids_s[(lf + 2) >> 10]) ? 1.f : 0.f;
        v.w = (((lf + 3) & 1023) == ids_s[(lf + 3) >> 10]) ? 1.f : 0.f;
        *(float4*)(b4 + 4 * idx) = v;
      }
    }
    if (t == 0) {
      sl[0] = (ids_s[0] == 0) ? 1.f : 0.f;
      sl[1] = (ids_s[0] == 1) ? 1.f : 0.f;
      sl[2] = (ids_s[0] == 2) ? 1.f : 0.f;
      sl[32767] = (ids_s[31] == 1023) ? 1.f : 0.f;
    }
  }

  // ---- outq: thread (p = t&31, g = t>>5) -> emb[id_p][g*32..+31] ----
  {
    const int p = t & 31, g = t >> 5;
    const int row = ids_s[p];
    const float* er = emb + (size_t)row * DIM + g * 32;
    float* ob = outq + (size_t)bb * CHW + hw0 + p;
#pragma unroll
    for (int i = 0; i < 8; ++i) {
      const float4 v = *(const float4*)(er + i * 4);
      const int c = g * 32 + i * 4;
      ob[(size_t)(c + 0) * 1024] = v.x;
      ob[(size_t)(c + 1) * 1024] = v.y;
      ob[(size_t)(c + 2) * 1024] = v.z;
      ob[(size_t)(c + 3) * 1024] = v.w;
    }
  }
}

// ---- loss_reduce: one block sums the 1024 per-block dmin partials ----
__global__ __launch_bounds__(256) void loss_reduce(
    const float* __restrict__ lws, float* __restrict__ loss) {
  __shared__ float red[4];
  const int t = threadIdx.x;
  float s = 0.f;
#pragma unroll
  for (int i = 0; i < 4; ++i) s += lws[t + i * 256];
#pragma unroll
  for (int o = 32; o > 0; o >>= 1) s += __shfl_down(s, o, 64);
  if ((t & 63) == 0) red[t >> 6] = s;
  __syncthreads();
  if (t == 0)
    *loss = (((red[0] + red[1]) + red[2]) + red[3]) * (1.25f / (float)QELEMS);
}

extern "C" void kernel_launch(void* const* d_in, const int* in_sizes, int n_in,
                              void* d_out, int out_size, void* d_ws, size_t ws_size,
                              hipStream_t stream) {
  const float* x   = (const float*)d_in[0];
  const float* emb = (const float*)d_in[1];
  float* out  = (float*)d_out;
  float* loss = out;                       // [1]
  float* outq = out + 1;                   // [8388608], 4B-aligned only
  float* enc  = out + 1 + QELEMS;          // [33554432], 4B-aligned only

  char* ws = (char*)d_ws;
  unsigned short* ehi  = (unsigned short*)ws;                  // 512 KB
  float*          esq  = (float*)(ws + 524288);                // 4 KB
  float*          xsq  = (float*)(ws + 528384);                // 128 KB
  float*          part = (float*)(ws + 659456);                // 1 MB
  unsigned int*   cand = (unsigned int*)(ws + 1708032);        // 4 MB
  unsigned short* xhi  = (unsigned short*)(ws + 5902336);      // 16 MB
  float*          lws  = (float*)(ws + 22679552);              // 4 KB
  // total ws use: ~22.7 MB

  prep_kernel<<<16 + 1024, 256, 0, stream>>>(x, emb, ehi, esq, xhi, xsq);
  dim3 cg(NPTS / 128, 8);
  coarse_kernel<<<cg, 256, 0, stream>>>(xhi, ehi, esq, xsq, part, cand);
  finish2_kernel<<<NPTS / 32, 256, 0, stream>>>(x, emb, esq, xsq, part, cand,
                                                outq, enc, lws);
  loss_reduce<<<1, 256, 0, stream>>>(lws, loss);
}